// Round 17
// baseline (46.443 us; speedup 1.0000x reference)
//
#include <hip/hip_runtime.h>

#define HOG_PI  3.14159265358979323846f
#define HOG_PI2 1.57079632679489661923f

__device__ __forceinline__ float dpp_from_left(float x) {  // lane i <- lane i-1
  return __int_as_float(__builtin_amdgcn_mov_dpp(__float_as_int(x), 0x130, 0xF, 0xF, true));
}
__device__ __forceinline__ float dpp_from_right(float x) {  // lane i <- lane i+1
  return __int_as_float(__builtin_amdgcn_mov_dpp(__float_as_int(x), 0x138, 0xF, 0xF, true));
}

// Accumulate 4 pixels (one float4 column) into thread-private LDS rows of 10
// bins (bin9 = unwrapped alias of bin0; merged at flush). RMW = ds_read2 +
// 2 adds + ds_write2 per pixel.
__device__ __forceinline__ void accum_quad(
    const float4 c0, const float4 c1, const float4 c2,
    const float4 p0, const float4 p1, const float4 p2,
    const float4 n0, const float4 n1, const float4 n2,
    int xq, float* __restrict__ partT) {
  float dxv[3][4], dyv[3][4];
#pragma unroll
  for (int c = 0; c < 3; ++c) {
    const float4 cc = (c == 0) ? c0 : (c == 1) ? c1 : c2;
    const float4 pp = (c == 0) ? p0 : (c == 1) ? p1 : p2;
    const float4 nn = (c == 0) ? n0 : (c == 1) ? n1 : n2;
    float lf = dpp_from_left(cc.w);   // prev lane's cc.w (VALU, no DS pipe)
    float rf = dpp_from_right(cc.x);  // next lane's cc.x
    if (xq == 0) lf = cc.x;           // edge clamp overrides boundary lanes
    if (xq == 31) rf = cc.w;
    dxv[c][0] = cc.y - lf;
    dxv[c][1] = cc.z - cc.x;
    dxv[c][2] = cc.w - cc.y;
    dxv[c][3] = rf - cc.z;
    dyv[c][0] = nn.x - pp.x;
    dyv[c][1] = nn.y - pp.y;
    dyv[c][2] = nn.z - pp.z;
    dyv[c][3] = nn.w - pp.w;
  }
#pragma unroll
  for (int i = 0; i < 4; ++i) {
    // channel argmax, first-max wins on ties (strict >)
    float dxs = dxv[0][i], dys = dyv[0][i];
    float g = dxs * dxs + dys * dys;
    const float g1 = dxv[1][i] * dxv[1][i] + dyv[1][i] * dyv[1][i];
    if (g1 > g) { dxs = dxv[1][i]; dys = dyv[1][i]; g = g1; }
    const float g2 = dxv[2][i] * dxv[2][i] + dyv[2][i] * dyv[2][i];
    if (g2 > g) { dxs = dxv[2][i]; dys = dyv[2][i]; g = g2; }
    const float mag = __builtin_amdgcn_sqrtf(g);  // raw v_sqrt_f32
    // unsigned angle mod pi: flip so dy >= 0
    if (dys < 0.0f) { dys = -dys; dxs = -dxs; }
    const float ax = fabsf(dxs);
    const float mn = fminf(ax, dys), mx = fmaxf(ax, dys);
    const float a = mn * __builtin_amdgcn_rcpf(fmaxf(mx, 1e-30f));
    const float sq = a * a;
    float th = ((((0.0208351f * sq - 0.0851330f) * sq + 0.1801410f) * sq
                 - 0.3302995f) * sq + 0.9998660f) * a;
    if (dys > ax) th = HOG_PI2 - th;
    if (dxs < 0.0f) th = HOG_PI - th;
    const float pos = th * (9.0f / HOG_PI) - 0.5f;  // [-0.5, 8.5]
    const float bf = floorf(pos);
    const float frac = pos - bf;
    const int b0 = (int)bf;  // [-1, 8]
    const int b0i = (b0 < 0) ? 8 : b0;  // 0..8; partner is b0i+1 (no wrap)
    const float w0 = mag * (1.0f - frac);
    const float w1 = mag * frac;
    float* row = partT + (i & 1) * 10 + b0i;  // even/odd px -> disjoint rows
    const float a0 = row[0];                  // ds_read2_b32
    const float a1 = row[1];
    row[0] = a0 + w0;                         // ds_write2_b32
    row[1] = a1 + w1;
  }
}

// One block per image, 512 threads = 16 bands (m=t>>5) x 32 float4-cols (xq).
// ROW-PAIR loop (8 iterations): 4-row register window (pa,ca,cb,nb); the next
// pair's 2 rows (6 float4 loads) are issued at iteration top and consumed one
// full iteration later (~860 issue-cycles of latency coverage, 2x the single-
// row pipeline R12 tested in the fatter-body regime). No launch_bounds.
__global__ void hog_kernel(
    const float* __restrict__ img, const int* __restrict__ targets,
    const int* __restrict__ camid, float* __restrict__ out, int B) {
  const int b = blockIdx.x;
  const int t = threadIdx.x;
  const float* im = img + (size_t)b * (3 * 256 * 128);

  __shared__ float lds[512 * 20];  // 40 KB; scatter rows, later cellh overlay
  float* const partT = lds + t * 20;

  const int xq = t & 31;   // float4 column 0..31
  const int m = t >> 5;    // cell band 0..15
  const int x0 = xq * 4;
  const int cx = xq >> 2;  // cell column 0..7
  const int r0 = m * 16;

#pragma unroll
  for (int j = 0; j < 20; ++j) partT[j] = 0.0f;

  const float* ch0 = im;
  const float* ch1 = im + 32768;
  const float* ch2 = im + 65536;

  const int rp = (r0 == 0) ? 0 : r0 - 1;
  // 4-row window: pa = ya-1, ca = ya, cb = ya+1, nb = ya+2   (ya = r0)
  float4 pa0 = *(const float4*)(ch0 + rp * 128 + x0);
  float4 pa1 = *(const float4*)(ch1 + rp * 128 + x0);
  float4 pa2 = *(const float4*)(ch2 + rp * 128 + x0);
  float4 ca0 = *(const float4*)(ch0 + r0 * 128 + x0);
  float4 ca1 = *(const float4*)(ch1 + r0 * 128 + x0);
  float4 ca2 = *(const float4*)(ch2 + r0 * 128 + x0);
  float4 cb0 = *(const float4*)(ch0 + (r0 + 1) * 128 + x0);
  float4 cb1 = *(const float4*)(ch1 + (r0 + 1) * 128 + x0);
  float4 cb2 = *(const float4*)(ch2 + (r0 + 1) * 128 + x0);
  float4 nb0 = *(const float4*)(ch0 + (r0 + 2) * 128 + x0);
  float4 nb1 = *(const float4*)(ch1 + (r0 + 2) * 128 + x0);
  float4 nb2 = *(const float4*)(ch2 + (r0 + 2) * 128 + x0);

#pragma unroll 1
  for (int j = 0; j < 8; ++j) {
    const int yb = r0 + 2 * j + 1;
    // prefetch next pair's rows yb+2, yb+3 (clamped); consumed next iteration
    const int ye = (yb + 2 > 255) ? 255 : yb + 2;
    const int yf = (yb + 3 > 255) ? 255 : yb + 3;
    const float4 e0 = *(const float4*)(ch0 + ye * 128 + x0);
    const float4 e1 = *(const float4*)(ch1 + ye * 128 + x0);
    const float4 e2 = *(const float4*)(ch2 + ye * 128 + x0);
    const float4 f0 = *(const float4*)(ch0 + yf * 128 + x0);
    const float4 f1 = *(const float4*)(ch1 + yf * 128 + x0);
    const float4 f2 = *(const float4*)(ch2 + yf * 128 + x0);

    // row ya: p=pa, c=ca, n=cb ; row yb: p=ca, c=cb, n=nb
    accum_quad(ca0, ca1, ca2, pa0, pa1, pa2, cb0, cb1, cb2, xq, partT);
    accum_quad(cb0, cb1, cb2, ca0, ca1, ca2, nb0, nb1, nb2, xq, partT);

    pa0 = cb0; pa1 = cb1; pa2 = cb2;
    ca0 = nb0; ca1 = nb1; ca2 = nb2;
    cb0 = e0;  cb1 = e1;  cb2 = e2;
    nb0 = f0;  nb1 = f1;  nb2 = f2;
  }

  // flush: merge 2 rows + fold bin9 (unwrapped) into bin0; reads into regs
  // BEFORE the barrier so the cellh overlay can't clobber unread data
  float hv[9];
#pragma unroll
  for (int k = 0; k < 9; ++k) hv[k] = partT[k] + partT[10 + k];
  hv[0] += partT[9] + partT[19];
  __syncthreads();

  float (*cellh)[8][9] = (float (*)[8][9])lds;  // overlay
#pragma unroll
  for (int k = 0; k < 9; ++k) {
    float v = hv[k];
    v += __shfl_xor(v, 1, 64);
    v += __shfl_xor(v, 2, 64);
    if ((xq & 3) == 0) cellh[m][cx][k] = v;
  }
  __syncthreads();

  float* outF = out + (size_t)b * 4096;
  if (t < 105) {
    const int by = t / 7;
    const int bx = t - by * 7;
    float v[36];
#pragma unroll
    for (int q = 0; q < 4; ++q) {
      const int cy = by + (q >> 1);
      const int ccx = bx + (q & 1);
#pragma unroll
      for (int k = 0; k < 9; ++k) v[q * 9 + k] = cellh[cy][ccx][k];
    }
    float ss = 0.0f;
#pragma unroll
    for (int jj = 0; jj < 36; ++jj) ss += v[jj] * v[jj];
    const float s1 = 1.0f / (sqrtf(ss) + 3.6f);  // sz*0.1 = 36*0.1
    float ss2 = 0.0f;
#pragma unroll
    for (int jj = 0; jj < 36; ++jj) {
      v[jj] = fminf(v[jj] * s1, 0.2f);
      ss2 += v[jj] * v[jj];
    }
    const float s2 = 1.0f / (sqrtf(ss2) + 1e-3f);
    float4* dst = (float4*)(outF + (by * 7 + bx) * 36);
#pragma unroll
    for (int q = 0; q < 9; ++q)
      dst[q] = make_float4(v[4 * q] * s2, v[4 * q + 1] * s2,
                           v[4 * q + 2] * s2, v[4 * q + 3] * s2);
  }
  // zero the pad region [3780, 4096)
  for (int i = 3780 + t; i < 4096; i += 512) outF[i] = 0.0f;
  // passthrough outputs
  if (t == 400) out[(size_t)B * 4096 + b] = (float)targets[b];
  if (t == 401) out[(size_t)B * 4096 + B + b] = (float)camid[b];
}

extern "C" void kernel_launch(void* const* d_in, const int* in_sizes, int n_in,
                              void* d_out, int out_size, void* d_ws, size_t ws_size,
                              hipStream_t stream) {
  const float* images = (const float*)d_in[0];
  const int* targets = (const int*)d_in[1];
  const int* camid = (const int*)d_in[2];
  float* out = (float*)d_out;
  const int B = in_sizes[1];  // 512
  hipLaunchKernelGGL(hog_kernel, dim3(B), dim3(512), 0, stream,
                     images, targets, camid, out, B);
}

// Round 18
// 43.532 us; speedup vs baseline: 1.0669x; 1.0669x over previous
//
#include <hip/hip_runtime.h>

#define HOG_PI  3.14159265358979323846f
#define HOG_PI2 1.57079632679489661923f

typedef float f2 __attribute__((ext_vector_type(2)));

__device__ __forceinline__ float dpp_from_left(float x) {  // lane i <- lane i-1
  return __int_as_float(__builtin_amdgcn_mov_dpp(__float_as_int(x), 0x130, 0xF, 0xF, true));
}
__device__ __forceinline__ float dpp_from_right(float x) {  // lane i <- lane i+1
  return __int_as_float(__builtin_amdgcn_mov_dpp(__float_as_int(x), 0x138, 0xF, 0xF, true));
}

// One scalar pixel tail: argmax -> angle -> bin scatter to LDS row.
// base-poly value comes in packed from the caller.
__device__ __forceinline__ void px_tail(
    float dxs, float dys, float g, float base, float* __restrict__ row) {
  const float mag = __builtin_amdgcn_sqrtf(g);
  // octant/sign reconstruction (replaces the old dy-flip):
  //   oct = |dy|>|dx| -> th = pi/2 - base ; sgn = dx*dy<0 -> th = pi - th
  const bool oct = fabsf(dys) > fabsf(dxs);
  float th = oct ? (HOG_PI2 - base) : base;
  if (dxs * dys < 0.0f) th = HOG_PI - th;
  const float pos = th * (9.0f / HOG_PI) - 0.5f;  // [-0.5, 8.5]
  const float bf = floorf(pos);
  const float frac = pos - bf;
  const int b0 = (int)bf;             // [-1, 8]
  const int b0i = (b0 < 0) ? 8 : b0;  // partner always b0i+1 (bin9 = alias 0)
  const float w0 = mag * (1.0f - frac);
  const float w1 = mag * frac;
  float* p = row + b0i;
  const float a0 = p[0];  // ds_read2_b32
  const float a1 = p[1];
  p[0] = a0 + w0;         // ds_write2_b32
  p[1] = a1 + w1;
}

// Accumulate 4 pixels (one float4 column). Packed-f32 (VOP3P) for the
// arithmetic bulk: gradients, |grad|^2 and the atan polynomial run on
// pixel-pairs as 2-wide vectors (v_pk_sub/mul/fma); compares/selects/trans
// stay scalar. Scatter: thread-private 10-bin LDS rows (R16).
__device__ __forceinline__ void accum_quad(
    const float4 c0, const float4 c1, const float4 c2,
    const float4 p0, const float4 p1, const float4 p2,
    const float4 n0, const float4 n1, const float4 n2,
    int xq, float* __restrict__ partT) {
  f2 dx[3][2], dy[3][2], g[3][2];
#pragma unroll
  for (int c = 0; c < 3; ++c) {
    const float4 cc = (c == 0) ? c0 : (c == 1) ? c1 : c2;
    const float4 pp = (c == 0) ? p0 : (c == 1) ? p1 : p2;
    const float4 nn = (c == 0) ? n0 : (c == 1) ? n1 : n2;
    float lf = dpp_from_left(cc.w);   // prev lane's cc.w (VALU, no DS pipe)
    float rf = dpp_from_right(cc.x);  // next lane's cc.x
    if (xq == 0) lf = cc.x;           // edge clamp overrides boundary lanes
    if (xq == 31) rf = cc.w;
    dx[c][0] = (f2){cc.y, cc.z} - (f2){lf, cc.x};    // v_pk_add (neg mod)
    dx[c][1] = (f2){cc.w, rf} - (f2){cc.y, cc.z};
    dy[c][0] = (f2){nn.x, nn.y} - (f2){pp.x, pp.y};
    dy[c][1] = (f2){nn.z, nn.w} - (f2){pp.z, pp.w};
    g[c][0] = dx[c][0] * dx[c][0] + dy[c][0] * dy[c][0];  // pk_mul + pk_fma
    g[c][1] = dx[c][1] * dx[c][1] + dy[c][1] * dy[c][1];
  }
#pragma unroll
  for (int p = 0; p < 2; ++p) {  // pixel pairs (2p, 2p+1)
    // scalar argmax per half, first-max wins on ties (strict >)
    float dxsA = dx[0][p].x, dysA = dy[0][p].x, gA = g[0][p].x;
    if (g[1][p].x > gA) { dxsA = dx[1][p].x; dysA = dy[1][p].x; gA = g[1][p].x; }
    if (g[2][p].x > gA) { dxsA = dx[2][p].x; dysA = dy[2][p].x; gA = g[2][p].x; }
    float dxsB = dx[0][p].y, dysB = dy[0][p].y, gB = g[0][p].y;
    if (g[1][p].y > gB) { dxsB = dx[1][p].y; dysB = dy[1][p].y; gB = g[1][p].y; }
    if (g[2][p].y > gB) { dxsB = dx[2][p].y; dysB = dy[2][p].y; gB = g[2][p].y; }
    // a = min/max(|dx|,|dy|) ratio (abs folds to VOP3 modifiers)
    const float mnA = fminf(fabsf(dxsA), fabsf(dysA));
    const float mxA = fmaxf(fmaxf(fabsf(dxsA), fabsf(dysA)), 1e-30f);
    const float aA = mnA * __builtin_amdgcn_rcpf(mxA);
    const float mnB = fminf(fabsf(dxsB), fabsf(dysB));
    const float mxB = fmaxf(fmaxf(fabsf(dxsB), fabsf(dysB)), 1e-30f);
    const float aB = mnB * __builtin_amdgcn_rcpf(mxB);
    // packed atan polynomial on the pair (4 pk_fma + pk_mul + pk_mul)
    const f2 av = {aA, aB};
    const f2 sq = av * av;
    const f2 base =
        ((((f2)(0.0208351f) * sq - (f2)(0.0851330f)) * sq + (f2)(0.1801410f)) *
             sq - (f2)(0.3302995f)) * sq * av + (f2)(0.9998660f) * av;
    px_tail(dxsA, dysA, gA, base.x, partT + ((2 * p) & 1) * 10);
    px_tail(dxsB, dysB, gB, base.y, partT + ((2 * p + 1) & 1) * 10);
  }
}

// One block per image, 512 threads = 16 bands (m=t>>5) x 32 float4-cols (xq).
// Scatter buffer [512 threads][2 rows][10 bins] = 40 KB -> 2 blocks/CU.
// cellh overlays the scatter buffer after flush (reads to regs first).
__global__ __launch_bounds__(512, 2) void hog_kernel(
    const float* __restrict__ img, const int* __restrict__ targets,
    const int* __restrict__ camid, float* __restrict__ out, int B) {
  const int b = blockIdx.x;
  const int t = threadIdx.x;
  const float* im = img + (size_t)b * (3 * 256 * 128);

  __shared__ float lds[512 * 20];  // 40 KB; scatter rows, later cellh overlay
  float* const partT = lds + t * 20;

  const int xq = t & 31;   // float4 column 0..31
  const int m = t >> 5;    // cell band 0..15
  const int x0 = xq * 4;
  const int cx = xq >> 2;  // cell column 0..7
  const int r0 = m * 16;

#pragma unroll
  for (int j = 0; j < 20; ++j) partT[j] = 0.0f;

  const float* ch0 = im;
  const float* ch1 = im + 32768;
  const float* ch2 = im + 65536;

  const int rp = (r0 == 0) ? 0 : r0 - 1;
  float4 p0 = *(const float4*)(ch0 + rp * 128 + x0);
  float4 p1 = *(const float4*)(ch1 + rp * 128 + x0);
  float4 p2 = *(const float4*)(ch2 + rp * 128 + x0);
  float4 c0 = *(const float4*)(ch0 + r0 * 128 + x0);
  float4 c1 = *(const float4*)(ch1 + r0 * 128 + x0);
  float4 c2 = *(const float4*)(ch2 + r0 * 128 + x0);
  float4 n0 = *(const float4*)(ch0 + (r0 + 1) * 128 + x0);
  float4 n1 = *(const float4*)(ch1 + (r0 + 1) * 128 + x0);
  float4 n2 = *(const float4*)(ch2 + (r0 + 1) * 128 + x0);

#pragma unroll 1
  for (int r = 0; r < 16; ++r) {
    // prefetch row r+1's 'n' (row y+2, clamped); issued before any use of n*
    const int y2 = r0 + r + 2;
    const int yc = (y2 > 255) ? 255 : y2;
    const float4 f0 = *(const float4*)(ch0 + yc * 128 + x0);
    const float4 f1 = *(const float4*)(ch1 + yc * 128 + x0);
    const float4 f2v = *(const float4*)(ch2 + yc * 128 + x0);

    accum_quad(c0, c1, c2, p0, p1, p2, n0, n1, n2, xq, partT);

    p0 = c0; p1 = c1; p2 = c2;
    c0 = n0; c1 = n1; c2 = n2;
    n0 = f0; n1 = f1; n2 = f2v;
  }

  // flush: merge 2 rows + fold bin9 (unwrapped) into bin0; reads into regs
  // BEFORE the barrier so the cellh overlay can't clobber unread data
  float hv[9];
#pragma unroll
  for (int k = 0; k < 9; ++k) hv[k] = partT[k] + partT[10 + k];
  hv[0] += partT[9] + partT[19];
  __syncthreads();

  float (*cellh)[8][9] = (float (*)[8][9])lds;  // overlay
#pragma unroll
  for (int k = 0; k < 9; ++k) {
    float v = hv[k];
    v += __shfl_xor(v, 1, 64);
    v += __shfl_xor(v, 2, 64);
    if ((xq & 3) == 0) cellh[m][cx][k] = v;
  }
  __syncthreads();

  float* outF = out + (size_t)b * 4096;
  if (t < 105) {
    const int by = t / 7;
    const int bx = t - by * 7;
    float v[36];
#pragma unroll
    for (int q = 0; q < 4; ++q) {
      const int cy = by + (q >> 1);
      const int ccx = bx + (q & 1);
#pragma unroll
      for (int k = 0; k < 9; ++k) v[q * 9 + k] = cellh[cy][ccx][k];
    }
    float ss = 0.0f;
#pragma unroll
    for (int jj = 0; jj < 36; ++jj) ss += v[jj] * v[jj];
    const float s1 = 1.0f / (sqrtf(ss) + 3.6f);  // sz*0.1 = 36*0.1
    float ss2 = 0.0f;
#pragma unroll
    for (int jj = 0; jj < 36; ++jj) {
      v[jj] = fminf(v[jj] * s1, 0.2f);
      ss2 += v[jj] * v[jj];
    }
    const float s2 = 1.0f / (sqrtf(ss2) + 1e-3f);
    float4* dst = (float4*)(outF + (by * 7 + bx) * 36);
#pragma unroll
    for (int q = 0; q < 9; ++q)
      dst[q] = make_float4(v[4 * q] * s2, v[4 * q + 1] * s2,
                           v[4 * q + 2] * s2, v[4 * q + 3] * s2);
  }
  // zero the pad region [3780, 4096)
  for (int i = 3780 + t; i < 4096; i += 512) outF[i] = 0.0f;
  // passthrough outputs
  if (t == 400) out[(size_t)B * 4096 + b] = (float)targets[b];
  if (t == 401) out[(size_t)B * 4096 + B + b] = (float)camid[b];
}

extern "C" void kernel_launch(void* const* d_in, const int* in_sizes, int n_in,
                              void* d_out, int out_size, void* d_ws, size_t ws_size,
                              hipStream_t stream) {
  const float* images = (const float*)d_in[0];
  const int* targets = (const int*)d_in[1];
  const int* camid = (const int*)d_in[2];
  float* out = (float*)d_out;
  const int B = in_sizes[1];  // 512
  hipLaunchKernelGGL(hog_kernel, dim3(B), dim3(512), 0, stream,
                     images, targets, camid, out, B);
}